// Round 4
// baseline (494.485 us; speedup 1.0000x reference)
//
#include <hip/hip_runtime.h>
#include <hip/hip_bf16.h>

typedef __hip_bfloat16 bf16;

static __device__ __forceinline__ unsigned short f2bf(float f) {
    unsigned u = __float_as_uint(f);
    return (unsigned short)((u + 0x7fffu + ((u >> 16) & 1u)) >> 16);
}
static __device__ __forceinline__ unsigned pack2(float lo, float hi) {
    return (((unsigned)f2bf(hi)) << 16) | (unsigned)f2bf(lo);
}
static __device__ __forceinline__ float bflo(unsigned u) { return __uint_as_float(u << 16); }
static __device__ __forceinline__ float bfhi(unsigned u) { return __uint_as_float(u & 0xffff0000u); }

// ---------------------------------------------------------------------------
// Kernel 1: separable positional-encoding tables (all f32).
//   EQc[c][n] = sum_fi sin(c*f_fi)*Wq[fi][n]    + cos(c*f_fi)*Wq[32+fi][n]
//   EQr[r][n] = sum_fi sin(r*f_fi)*Wq[64+fi][n] + cos(r*f_fi)*Wq[96+fi][n] + bq[n]
// ---------------------------------------------------------------------------
__global__ __launch_bounds__(256) void enc_tables(
    const float* __restrict__ Wq, const float* __restrict__ bq,
    const float* __restrict__ Wk, const float* __restrict__ bk,
    float* __restrict__ EQc, float* __restrict__ EQr,
    float* __restrict__ EKc, float* __restrict__ EKr)
{
    const int c   = blockIdx.x;          // coordinate 0..127 (row or col)
    const int ch  = threadIdx.x & 127;   // output channel
    const int isk = threadIdx.x >> 7;    // 0: q tables, 1: k tables
    const float* W = isk ? Wk : Wq;
    const float* b = isk ? bk : bq;
    const float FSTEP = (float)(3.14 / 200.0);
    float accC = 0.f, accR = 0.f;
    for (int fi = 0; fi < 32; ++fi) {
        float f = (float)fi * FSTEP;
        float a = (float)c * f;
        float s = sinf(a), co = cosf(a);
        accC = fmaf(s,  W[fi * 128 + ch],        accC);
        accC = fmaf(co, W[(32 + fi) * 128 + ch], accC);
        accR = fmaf(s,  W[(64 + fi) * 128 + ch], accR);
        accR = fmaf(co, W[(96 + fi) * 128 + ch], accR);
    }
    accR += b[ch];
    (isk ? EKc : EQc)[c * 128 + ch] = accC;
    (isk ? EKr : EQr)[c * 128 + ch] = accR;
}

// ---------------------------------------------------------------------------
// Kernel 2: fused QKV GEMM. M=163840 tokens, K=128, N=384 ([q|k|v]).
// f32 inputs, fp32 math, bf16 workspace outputs.
// ---------------------------------------------------------------------------
__global__ __launch_bounds__(256) void qkv_gemm(
    const float* __restrict__ x,
    const float* __restrict__ Wq, const float* __restrict__ Wk, const float* __restrict__ Wv,
    const float* __restrict__ EQc, const float* __restrict__ EQr,
    const float* __restrict__ EKc, const float* __restrict__ EKr,
    const float* __restrict__ bv,
    bf16* __restrict__ qb, bf16* __restrict__ kb, bf16* __restrict__ vb)
{
    __shared__ float Xs[64][128];   // 32 KB
    __shared__ float Ws[128][64];   // 32 KB
    const int tid = threadIdx.x;
    const int mb = blockIdx.x;      // 0..2559
    const int nb = blockIdx.y;      // 0..5

    const float* xbase = x + (size_t)mb * (64 * 128);
#pragma unroll
    for (int i = 0; i < 8; ++i) {
        int idx = tid + i * 256;
        int m = idx >> 5, c4 = (idx & 31) << 2;
        *(float4*)&Xs[m][c4] = *(const float4*)(xbase + m * 128 + c4);
    }
    const float* Wsrc = (nb < 2) ? Wq : ((nb < 4) ? Wk : Wv);
    const int wc0 = (nb & 1) * 64;
#pragma unroll
    for (int i = 0; i < 8; ++i) {
        int idx = tid + i * 256;
        int k = idx >> 4, n4 = (idx & 15) << 2;
        *(float4*)&Ws[k][n4] = *(const float4*)(Wsrc + k * 128 + wc0 + n4);
    }
    __syncthreads();

    const int ty = tid >> 4, tx = tid & 15;
    const int m0 = ty << 2, n0 = tx << 2;
    float acc[4][4] = {};
#pragma unroll 8
    for (int k = 0; k < 128; ++k) {
        float a0 = Xs[m0 + 0][k];
        float a1 = Xs[m0 + 1][k];
        float a2 = Xs[m0 + 2][k];
        float a3 = Xs[m0 + 3][k];
        float4 bb = *(const float4*)&Ws[k][n0];
        acc[0][0] = fmaf(a0, bb.x, acc[0][0]); acc[0][1] = fmaf(a0, bb.y, acc[0][1]);
        acc[0][2] = fmaf(a0, bb.z, acc[0][2]); acc[0][3] = fmaf(a0, bb.w, acc[0][3]);
        acc[1][0] = fmaf(a1, bb.x, acc[1][0]); acc[1][1] = fmaf(a1, bb.y, acc[1][1]);
        acc[1][2] = fmaf(a1, bb.z, acc[1][2]); acc[1][3] = fmaf(a1, bb.w, acc[1][3]);
        acc[2][0] = fmaf(a2, bb.x, acc[2][0]); acc[2][1] = fmaf(a2, bb.y, acc[2][1]);
        acc[2][2] = fmaf(a2, bb.z, acc[2][2]); acc[2][3] = fmaf(a2, bb.w, acc[2][3]);
        acc[3][0] = fmaf(a3, bb.x, acc[3][0]); acc[3][1] = fmaf(a3, bb.y, acc[3][1]);
        acc[3][2] = fmaf(a3, bb.z, acc[3][2]); acc[3][3] = fmaf(a3, bb.w, acc[3][3]);
    }

    bf16* dst = (nb < 2) ? qb : ((nb < 4) ? kb : vb);
#pragma unroll
    for (int i = 0; i < 4; ++i) {
        size_t gt = (size_t)mb * 64 + m0 + i;
        int s = (int)(gt & 16383);          // spatial token (16384/image)
        int row = s >> 7, col = s & 127;
        int ch = wc0 + n0;
        float v0 = acc[i][0], v1 = acc[i][1], v2 = acc[i][2], v3 = acc[i][3];
        if (nb < 2) {
            const float* ec = EQc + col * 128 + ch;
            const float* er = EQr + row * 128 + ch;
            v0 += ec[0] + er[0]; v1 += ec[1] + er[1];
            v2 += ec[2] + er[2]; v3 += ec[3] + er[3];
        } else if (nb < 4) {
            const float* ec = EKc + col * 128 + ch;
            const float* er = EKr + row * 128 + ch;
            v0 += ec[0] + er[0]; v1 += ec[1] + er[1];
            v2 += ec[2] + er[2]; v3 += ec[3] + er[3];
        } else {
            v0 += bv[ch + 0]; v1 += bv[ch + 1]; v2 += bv[ch + 2]; v3 += bv[ch + 3];
        }
        unsigned* o = (unsigned*)(dst + gt * 128 + ch);
        o[0] = pack2(v0, v1);
        o[1] = pack2(v2, v3);
    }
}

// ---------------------------------------------------------------------------
// Kernel 3: windowed attention + output projection, fused. f32 OUTPUT.
// One block per (window, batch), 256 thr = 4 heads x 64 queries.
// ---------------------------------------------------------------------------
__global__ __launch_bounds__(256) void attn_o(
    const bf16* __restrict__ qb, const bf16* __restrict__ kb, const bf16* __restrict__ vb,
    const float* __restrict__ Wo, const float* __restrict__ bo,
    float* __restrict__ out)
{
    __shared__ float kls[64][128];  // 32 KB (phase2: Wo as bf16 [128][128])
    __shared__ float vls[64][128];  // 32 KB (phase2: aoT f32 [128][64]; phase3: ols f32 [64][128])
    const int w = blockIdx.x;       // 0..255
    const int b = blockIdx.y;       // 0..9
    const int wy = w >> 4, wx = w & 15;
    const int g = b >> 1;           // bn = 2
    int swy = wy, swx = wx;
    if (g == 0)      { if (wy < 15) swy = wy + 1; }   // up
    else if (g == 1) { if (wy > 0)  swy = wy - 1; }   // down
    else if (g == 2) { if (wx < 15) swx = wx + 1; }   // left
    else if (g == 3) { if (wx > 0)  swx = wx - 1; }   // right
    const int tid = threadIdx.x;
    const size_t bbase = (size_t)b * 16384;

#pragma unroll
    for (int i = 0; i < 8; ++i) {
        int idx = tid + i * 256;
        int j = idx >> 5, c4 = (idx & 31) << 2;
        int tok = ((swy * 8 + (j >> 3)) << 7) + (swx << 3) + (j & 7);
        size_t off = (bbase + tok) * 128 + c4;
        uint2 rk = *(const uint2*)(kb + off);
        kls[j][c4 + 0] = bflo(rk.x); kls[j][c4 + 1] = bfhi(rk.x);
        kls[j][c4 + 2] = bflo(rk.y); kls[j][c4 + 3] = bfhi(rk.y);
        uint2 rv = *(const uint2*)(vb + off);
        vls[j][c4 + 0] = bflo(rv.x); vls[j][c4 + 1] = bfhi(rv.x);
        vls[j][c4 + 2] = bflo(rv.y); vls[j][c4 + 3] = bfhi(rv.y);
    }
    __syncthreads();

    const int h = tid >> 6, qi = tid & 63;      // h uniform per wave
    const int qtok = ((wy * 8 + (qi >> 3)) << 7) + (wx << 3) + (qi & 7);
    const bf16* qrow = qb + (bbase + qtok) * 128 + (h << 5);
    float q[32];
#pragma unroll
    for (int i = 0; i < 4; ++i) {
        uint4 r = *(const uint4*)(qrow + i * 8);
        q[i*8+0] = bflo(r.x); q[i*8+1] = bfhi(r.x);
        q[i*8+2] = bflo(r.y); q[i*8+3] = bfhi(r.y);
        q[i*8+4] = bflo(r.z); q[i*8+5] = bfhi(r.z);
        q[i*8+6] = bflo(r.w); q[i*8+7] = bfhi(r.w);
    }

    // single-pass softmax (|logit| <~ 1.5 for this data; shift-invariant)
    const float scale = 0.17677669529663689f;   // 32^-0.5
    float ssum = 0.0f;
    float acc[32] = {};
#pragma unroll 2
    for (int j = 0; j < 64; ++j) {
        const float4* kr = (const float4*)&kls[j][h << 5];
        float d = 0.0f;
#pragma unroll
        for (int c = 0; c < 8; ++c) {
            float4 kv = kr[c];
            d = fmaf(q[c*4+0], kv.x, d);
            d = fmaf(q[c*4+1], kv.y, d);
            d = fmaf(q[c*4+2], kv.z, d);
            d = fmaf(q[c*4+3], kv.w, d);
        }
        float p = __expf(d * scale);
        ssum += p;
        const float4* vr = (const float4*)&vls[j][h << 5];
#pragma unroll
        for (int c = 0; c < 8; ++c) {
            float4 vv = vr[c];
            acc[c*4+0] = fmaf(p, vv.x, acc[c*4+0]);
            acc[c*4+1] = fmaf(p, vv.y, acc[c*4+1]);
            acc[c*4+2] = fmaf(p, vv.z, acc[c*4+2]);
            acc[c*4+3] = fmaf(p, vv.w, acc[c*4+3]);
        }
    }
    float inv = 1.0f / ssum;

    __syncthreads();   // everyone done reading kls/vls

    // phase 2: ao^T (f32 [128][64]) into vls area (conflict-free: qi = lane)
    float* aoT = &vls[0][0];
#pragma unroll
    for (int j = 0; j < 32; ++j)
        aoT[((h << 5) + j) * 64 + qi] = acc[j] * inv;

    // stage Wo (f32 -> bf16 [128][128]) into kls area
    bf16* wols = (bf16*)&kls[0][0];
#pragma unroll
    for (int i = 0; i < 16; ++i) {
        int idx = tid + i * 256;               // 4096 float4-quads
        int k = idx >> 5, n4 = (idx & 31) << 2;
        float4 wv = *(const float4*)(Wo + k * 128 + n4);
        unsigned* dst = (unsigned*)(wols + k * 128 + n4);
        dst[0] = pack2(wv.x, wv.y);
        dst[1] = pack2(wv.z, wv.w);
    }
    __syncthreads();

    // out[qtok][h*32+j] = sum_k ao[qtok][k] * Wo[k][h*32+j] + bo
    float o32[32] = {};
#pragma unroll 4
    for (int k = 0; k < 128; ++k) {
        float a = aoT[(k << 6) + qi];                           // 2-way, free
        const uint4* wr = (const uint4*)(wols + (k << 7) + (h << 5)); // broadcast
#pragma unroll
        for (int gg = 0; gg < 4; ++gg) {
            uint4 wv = wr[gg];
            o32[gg*8+0] = fmaf(a, bflo(wv.x), o32[gg*8+0]);
            o32[gg*8+1] = fmaf(a, bfhi(wv.x), o32[gg*8+1]);
            o32[gg*8+2] = fmaf(a, bflo(wv.y), o32[gg*8+2]);
            o32[gg*8+3] = fmaf(a, bfhi(wv.y), o32[gg*8+3]);
            o32[gg*8+4] = fmaf(a, bflo(wv.z), o32[gg*8+4]);
            o32[gg*8+5] = fmaf(a, bfhi(wv.z), o32[gg*8+5]);
            o32[gg*8+6] = fmaf(a, bflo(wv.w), o32[gg*8+6]);
            o32[gg*8+7] = fmaf(a, bfhi(wv.w), o32[gg*8+7]);
        }
    }
    __syncthreads();   // aoT reads done; reuse vls area for ols

    // phase 3: stage o32 (+bo) into ols[64][128] with XOR swizzle, then
    // cooperative coalesced f32 store.
    const int ch0 = h << 5;
    float* ols = &vls[0][0];
    const int xm = (qi & 31) << 2;
#pragma unroll
    for (int jj = 0; jj < 8; ++jj) {
        int cc = ch0 + (jj << 2);
        float4 o4;
        o4.x = o32[jj*4+0] + bo[cc+0];
        o4.y = o32[jj*4+1] + bo[cc+1];
        o4.z = o32[jj*4+2] + bo[cc+2];
        o4.w = o32[jj*4+3] + bo[cc+3];
        *(float4*)&ols[(qi << 7) + (cc ^ xm)] = o4;
    }
    __syncthreads();

#pragma unroll
    for (int i = 0; i < 8; ++i) {
        int idx = tid + i * 256;
        int m = idx >> 5, c4 = (idx & 31) << 2;
        int tok = ((wy * 8 + (m >> 3)) << 7) + (wx << 3) + (m & 7);
        float4 o4 = *(const float4*)&ols[(m << 7) + (c4 ^ ((m & 31) << 2))];
        *(float4*)(out + (bbase + tok) * 128 + c4) = o4;
    }
}

// ---------------------------------------------------------------------------
extern "C" void kernel_launch(void* const* d_in, const int* in_sizes, int n_in,
                              void* d_out, int out_size, void* d_ws, size_t ws_size,
                              hipStream_t stream)
{
    const float* x  = (const float*)d_in[0];
    const float* Wq = (const float*)d_in[1];
    const float* bq = (const float*)d_in[2];
    const float* Wk = (const float*)d_in[3];
    const float* bk = (const float*)d_in[4];
    const float* Wv = (const float*)d_in[5];
    const float* bv = (const float*)d_in[6];
    const float* Wo = (const float*)d_in[7];
    const float* bo = (const float*)d_in[8];

    char* ws = (char*)d_ws;
    float* EQc = (float*)(ws);                 //   65,536 B
    float* EQr = (float*)(ws + 65536);         //   65,536 B
    float* EKc = (float*)(ws + 131072);        //   65,536 B
    float* EKr = (float*)(ws + 196608);        //   65,536 B
    bf16*  qb  = (bf16*)(ws + 262144);         // 41,943,040 B (163840x128 bf16)
    bf16*  kb  = (bf16*)(ws + 42205184);       // 41,943,040 B
    bf16*  vb  = (bf16*)(ws + 84148224);       // 41,943,040 B  (end: 126,091,264)
    float* outp = (float*)d_out;

    enc_tables<<<dim3(128),     256, 0, stream>>>(Wq, bq, Wk, bk, EQc, EQr, EKc, EKr);
    qkv_gemm  <<<dim3(2560, 6), 256, 0, stream>>>(x, Wq, Wk, Wv, EQc, EQr, EKc, EKr, bv, qb, kb, vb);
    attn_o    <<<dim3(256, 10), 256, 0, stream>>>(qb, kb, vb, Wo, bo, outp);
}

// Round 6
// 361.118 us; speedup vs baseline: 1.3693x; 1.3693x over previous
//
#include <hip/hip_runtime.h>
#include <hip/hip_bf16.h>

typedef __hip_bfloat16 bf16;
typedef short bf16x8 __attribute__((ext_vector_type(8)));
typedef float f32x4 __attribute__((ext_vector_type(4)));

static __device__ __forceinline__ unsigned short f2bf(float f) {
    unsigned u = __float_as_uint(f);
    return (unsigned short)((u + 0x7fffu + ((u >> 16) & 1u)) >> 16);
}
static __device__ __forceinline__ unsigned pack2(float lo, float hi) {
    return (((unsigned)f2bf(hi)) << 16) | (unsigned)f2bf(lo);
}
static __device__ __forceinline__ float bflo(unsigned u) { return __uint_as_float(u << 16); }
static __device__ __forceinline__ float bfhi(unsigned u) { return __uint_as_float(u & 0xffff0000u); }

// ---------------------------------------------------------------------------
// Kernel 1: separable positional-encoding tables (all f32).
// ---------------------------------------------------------------------------
__global__ __launch_bounds__(256) void enc_tables(
    const float* __restrict__ Wq, const float* __restrict__ bq,
    const float* __restrict__ Wk, const float* __restrict__ bk,
    float* __restrict__ EQc, float* __restrict__ EQr,
    float* __restrict__ EKc, float* __restrict__ EKr)
{
    const int c   = blockIdx.x;          // coordinate 0..127 (row or col)
    const int ch  = threadIdx.x & 127;   // output channel
    const int isk = threadIdx.x >> 7;    // 0: q tables, 1: k tables
    const float* W = isk ? Wk : Wq;
    const float* b = isk ? bk : bq;
    const float FSTEP = (float)(3.14 / 200.0);
    float accC = 0.f, accR = 0.f;
    for (int fi = 0; fi < 32; ++fi) {
        float f = (float)fi * FSTEP;
        float a = (float)c * f;
        float s = sinf(a), co = cosf(a);
        accC = fmaf(s,  W[fi * 128 + ch],        accC);
        accC = fmaf(co, W[(32 + fi) * 128 + ch], accC);
        accR = fmaf(s,  W[(64 + fi) * 128 + ch], accR);
        accR = fmaf(co, W[(96 + fi) * 128 + ch], accR);
    }
    accR += b[ch];
    (isk ? EKc : EQc)[c * 128 + ch] = accC;
    (isk ? EKr : EQr)[c * 128 + ch] = accR;
}

// ---------------------------------------------------------------------------
// Kernel 1b: transpose+convert weights: WT[j][n][k] = W_j[k][n] as bf16.
// ---------------------------------------------------------------------------
__global__ __launch_bounds__(128) void prep_w(
    const float* __restrict__ Wq, const float* __restrict__ Wk,
    const float* __restrict__ Wv, unsigned short* __restrict__ WT)
{
    const int j = blockIdx.x;       // 0..2
    const int n = blockIdx.y;       // 0..127
    const int k = threadIdx.x;      // 0..127
    const float* W = (j == 0) ? Wq : ((j == 1) ? Wk : Wv);
    WT[((size_t)j * 128 + n) * 128 + k] = f2bf(W[k * 128 + n]);
}

// ---------------------------------------------------------------------------
// Kernel 2: QKV GEMM via MFMA. Tile 128 tokens x 128 ch, K=128.
// grid (1280 m-tiles, 3 outputs). 256 thr = 4 waves; wave w handles rows
// w*32..w*32+31 (2 row-tiles), all 8 col-tiles. mfma_f32_16x16x32_bf16.
// LDS XOR-swizzled (byte ^= (row&7)<<4) on both stage and read.
// ---------------------------------------------------------------------------
__global__ __launch_bounds__(256) void qkv_mfma(
    const float* __restrict__ x,
    const unsigned short* __restrict__ WT,
    const float* __restrict__ EQc, const float* __restrict__ EQr,
    const float* __restrict__ EKc, const float* __restrict__ EKr,
    const float* __restrict__ bv,
    unsigned short* __restrict__ qb, unsigned short* __restrict__ kb,
    unsigned short* __restrict__ vb)
{
    __shared__ unsigned short xs[128 * 128];   // 32 KB, swizzled [m][k]
    __shared__ unsigned short wt[128 * 128];   // 32 KB, swizzled [n][k]
    const int tid = threadIdx.x;
    const int mb = blockIdx.x;    // 0..1279
    const int nb = blockIdx.y;    // 0: q, 1: k, 2: v

    // stage x tile (f32 -> bf16, swizzled): 2048 chunks of 8 elems
    const float* xbase = x + (size_t)mb * (128 * 128);
#pragma unroll
    for (int i = 0; i < 8; ++i) {
        int idx = tid + i * 256;
        int m = idx >> 4, c8 = (idx & 15) << 3;
        float4 f0 = *(const float4*)(xbase + m * 128 + c8);
        float4 f1 = *(const float4*)(xbase + m * 128 + c8 + 4);
        unsigned off = (unsigned)(m * 256 + ((c8 * 2) ^ ((m & 7) << 4)));
        unsigned* d = (unsigned*)((char*)xs + off);
        d[0] = pack2(f0.x, f0.y); d[1] = pack2(f0.z, f0.w);
        d[2] = pack2(f1.x, f1.y); d[3] = pack2(f1.z, f1.w);
    }
    // stage WT[nb] (bf16 copy, swizzled): 2048 chunks of 16B  [FIXED: was 1024]
    const unsigned short* wsrc = WT + (size_t)nb * (128 * 128);
#pragma unroll
    for (int i = 0; i < 8; ++i) {
        int idx = tid + i * 256;
        int n = idx >> 4, cb = (idx & 15) << 4;   // byte offset in row
        uint4 r = *(const uint4*)(wsrc + n * 128 + (idx & 15) * 8);
        unsigned off = (unsigned)(n * 256 + (cb ^ ((n & 7) << 4)));
        *(uint4*)((char*)wt + off) = r;
    }
    __syncthreads();

    const int lane = tid & 63;
    const int wv4  = tid >> 6;          // wave id 0..3
    const int wbase = wv4 << 5;         // row base (32 rows per wave)
    const int lo16 = (lane >> 4) << 4;  // k-group byte offset
    const int lx   = (lane & 7) << 4;   // xor value (row&7)<<4 for row=lane&15

    f32x4 acc[2][8] = {};
#pragma unroll
    for (int ks = 0; ks < 4; ++ks) {
        bf16x8 af[2], bfr[8];
        const int kb0 = ks * 64 + lo16;
#pragma unroll
        for (int rt = 0; rt < 2; ++rt) {
            int row = wbase + rt * 16 + (lane & 15);
            af[rt] = *(const bf16x8*)((const char*)xs + row * 256 + (kb0 ^ lx));
        }
#pragma unroll
        for (int ct = 0; ct < 8; ++ct) {
            int n = ct * 16 + (lane & 15);
            bfr[ct] = *(const bf16x8*)((const char*)wt + n * 256 + (kb0 ^ lx));
        }
#pragma unroll
        for (int rt = 0; rt < 2; ++rt)
#pragma unroll
            for (int ct = 0; ct < 8; ++ct)
                acc[rt][ct] = __builtin_amdgcn_mfma_f32_16x16x32_bf16(
                    af[rt], bfr[ct], acc[rt][ct], 0, 0, 0);
    }

    // epilogue: token t = mb*128 + m  ->  image row = mb&127 (uniform), col = m
    const int rowimg = mb & 127;
    unsigned short* dstp = (nb == 0) ? qb : ((nb == 1) ? kb : vb);
#pragma unroll
    for (int rt = 0; rt < 2; ++rt) {
#pragma unroll
        for (int r = 0; r < 4; ++r) {
            int m = wbase + rt * 16 + ((lane >> 4) << 2) + r;
            size_t t = (size_t)mb * 128 + m;
#pragma unroll
            for (int ct = 0; ct < 8; ++ct) {
                int ch = ct * 16 + (lane & 15);
                float val = acc[rt][ct][r];
                if (nb == 0)      val += EQc[m * 128 + ch] + EQr[rowimg * 128 + ch];
                else if (nb == 1) val += EKc[m * 128 + ch] + EKr[rowimg * 128 + ch];
                else              val += bv[ch];
                dstp[t * 128 + ch] = f2bf(val);
            }
        }
    }
}

// ---------------------------------------------------------------------------
// Kernel 3: windowed attention + output projection, fused. f32 OUTPUT.
// One block per (window, batch), 256 thr = 4 heads x 64 queries.
// ---------------------------------------------------------------------------
__global__ __launch_bounds__(256) void attn_o(
    const bf16* __restrict__ qb, const bf16* __restrict__ kb, const bf16* __restrict__ vb,
    const float* __restrict__ Wo, const float* __restrict__ bo,
    float* __restrict__ out)
{
    __shared__ float kls[64][128];  // 32 KB (phase2: Wo as bf16 [128][128])
    __shared__ float vls[64][128];  // 32 KB (phase2: aoT f32; phase3: ols f32)
    const int w = blockIdx.x;       // 0..255
    const int b = blockIdx.y;       // 0..9
    const int wy = w >> 4, wx = w & 15;
    const int g = b >> 1;           // bn = 2
    int swy = wy, swx = wx;
    if (g == 0)      { if (wy < 15) swy = wy + 1; }   // up
    else if (g == 1) { if (wy > 0)  swy = wy - 1; }   // down
    else if (g == 2) { if (wx < 15) swx = wx + 1; }   // left
    else if (g == 3) { if (wx > 0)  swx = wx - 1; }   // right
    const int tid = threadIdx.x;
    const size_t bbase = (size_t)b * 16384;

#pragma unroll
    for (int i = 0; i < 8; ++i) {
        int idx = tid + i * 256;
        int j = idx >> 5, c4 = (idx & 31) << 2;
        int tok = ((swy * 8 + (j >> 3)) << 7) + (swx << 3) + (j & 7);
        size_t off = (bbase + tok) * 128 + c4;
        uint2 rk = *(const uint2*)(kb + off);
        kls[j][c4 + 0] = bflo(rk.x); kls[j][c4 + 1] = bfhi(rk.x);
        kls[j][c4 + 2] = bflo(rk.y); kls[j][c4 + 3] = bfhi(rk.y);
        uint2 rv = *(const uint2*)(vb + off);
        vls[j][c4 + 0] = bflo(rv.x); vls[j][c4 + 1] = bfhi(rv.x);
        vls[j][c4 + 2] = bflo(rv.y); vls[j][c4 + 3] = bfhi(rv.y);
    }
    __syncthreads();

    const int h = tid >> 6, qi = tid & 63;      // h uniform per wave
    const int qtok = ((wy * 8 + (qi >> 3)) << 7) + (wx << 3) + (qi & 7);
    const bf16* qrow = qb + (bbase + qtok) * 128 + (h << 5);
    float q[32];
#pragma unroll
    for (int i = 0; i < 4; ++i) {
        uint4 r = *(const uint4*)(qrow + i * 8);
        q[i*8+0] = bflo(r.x); q[i*8+1] = bfhi(r.x);
        q[i*8+2] = bflo(r.y); q[i*8+3] = bfhi(r.y);
        q[i*8+4] = bflo(r.z); q[i*8+5] = bfhi(r.z);
        q[i*8+6] = bflo(r.w); q[i*8+7] = bfhi(r.w);
    }

    // single-pass softmax (|logit| small; shift-invariant)
    const float scale = 0.17677669529663689f;   // 32^-0.5
    float ssum = 0.0f;
    float acc[32] = {};
#pragma unroll 2
    for (int j = 0; j < 64; ++j) {
        const float4* kr = (const float4*)&kls[j][h << 5];
        float d = 0.0f;
#pragma unroll
        for (int c = 0; c < 8; ++c) {
            float4 kv = kr[c];
            d = fmaf(q[c*4+0], kv.x, d);
            d = fmaf(q[c*4+1], kv.y, d);
            d = fmaf(q[c*4+2], kv.z, d);
            d = fmaf(q[c*4+3], kv.w, d);
        }
        float p = __expf(d * scale);
        ssum += p;
        const float4* vr = (const float4*)&vls[j][h << 5];
#pragma unroll
        for (int c = 0; c < 8; ++c) {
            float4 vv = vr[c];
            acc[c*4+0] = fmaf(p, vv.x, acc[c*4+0]);
            acc[c*4+1] = fmaf(p, vv.y, acc[c*4+1]);
            acc[c*4+2] = fmaf(p, vv.z, acc[c*4+2]);
            acc[c*4+3] = fmaf(p, vv.w, acc[c*4+3]);
        }
    }
    float inv = 1.0f / ssum;

    __syncthreads();   // everyone done reading kls/vls

    // phase 2: ao^T (f32 [128][64]) into vls area (conflict-free: qi = lane)
    float* aoT = &vls[0][0];
#pragma unroll
    for (int j = 0; j < 32; ++j)
        aoT[((h << 5) + j) * 64 + qi] = acc[j] * inv;

    // stage Wo (f32 -> bf16 [128][128]) into kls area
    bf16* wols = (bf16*)&kls[0][0];
#pragma unroll
    for (int i = 0; i < 16; ++i) {
        int idx = tid + i * 256;               // 4096 float4-quads
        int k = idx >> 5, n4 = (idx & 31) << 2;
        float4 wv = *(const float4*)(Wo + k * 128 + n4);
        unsigned* dst = (unsigned*)(wols + k * 128 + n4);
        dst[0] = pack2(wv.x, wv.y);
        dst[1] = pack2(wv.z, wv.w);
    }
    __syncthreads();

    // out[qtok][h*32+j] = sum_k ao[qtok][k] * Wo[k][h*32+j] + bo
    float o32[32] = {};
#pragma unroll 4
    for (int k = 0; k < 128; ++k) {
        float a = aoT[(k << 6) + qi];                           // 2-way, free
        const uint4* wr = (const uint4*)(wols + (k << 7) + (h << 5)); // broadcast
#pragma unroll
        for (int gg = 0; gg < 4; ++gg) {
            uint4 wv = wr[gg];
            o32[gg*8+0] = fmaf(a, bflo(wv.x), o32[gg*8+0]);
            o32[gg*8+1] = fmaf(a, bfhi(wv.x), o32[gg*8+1]);
            o32[gg*8+2] = fmaf(a, bflo(wv.y), o32[gg*8+2]);
            o32[gg*8+3] = fmaf(a, bfhi(wv.y), o32[gg*8+3]);
            o32[gg*8+4] = fmaf(a, bflo(wv.z), o32[gg*8+4]);
            o32[gg*8+5] = fmaf(a, bfhi(wv.z), o32[gg*8+5]);
            o32[gg*8+6] = fmaf(a, bflo(wv.w), o32[gg*8+6]);
            o32[gg*8+7] = fmaf(a, bfhi(wv.w), o32[gg*8+7]);
        }
    }
    __syncthreads();   // aoT reads done; reuse vls area for ols

    // phase 3: stage o32 (+bo) into ols[64][128] swizzled, then coalesced store
    const int ch0 = h << 5;
    float* ols = &vls[0][0];
    const int xm = (qi & 31) << 2;
#pragma unroll
    for (int jj = 0; jj < 8; ++jj) {
        int cc = ch0 + (jj << 2);
        float4 o4;
        o4.x = o32[jj*4+0] + bo[cc+0];
        o4.y = o32[jj*4+1] + bo[cc+1];
        o4.z = o32[jj*4+2] + bo[cc+2];
        o4.w = o32[jj*4+3] + bo[cc+3];
        *(float4*)&ols[(qi << 7) + (cc ^ xm)] = o4;
    }
    __syncthreads();

#pragma unroll
    for (int i = 0; i < 8; ++i) {
        int idx = tid + i * 256;
        int m = idx >> 5, c4 = (idx & 31) << 2;
        int tok = ((wy * 8 + (m >> 3)) << 7) + (wx << 3) + (m & 7);
        float4 o4 = *(const float4*)&ols[(m << 7) + (c4 ^ ((m & 31) << 2))];
        *(float4*)(out + (bbase + tok) * 128 + c4) = o4;
    }
}

// ---------------------------------------------------------------------------
extern "C" void kernel_launch(void* const* d_in, const int* in_sizes, int n_in,
                              void* d_out, int out_size, void* d_ws, size_t ws_size,
                              hipStream_t stream)
{
    const float* x  = (const float*)d_in[0];
    const float* Wq = (const float*)d_in[1];
    const float* bq = (const float*)d_in[2];
    const float* Wk = (const float*)d_in[3];
    const float* bk = (const float*)d_in[4];
    const float* Wv = (const float*)d_in[5];
    const float* bv = (const float*)d_in[6];
    const float* Wo = (const float*)d_in[7];
    const float* bo = (const float*)d_in[8];

    char* ws = (char*)d_ws;
    float* EQc = (float*)(ws);                       //  65,536 B
    float* EQr = (float*)(ws + 65536);               //  65,536 B
    float* EKc = (float*)(ws + 131072);              //  65,536 B
    float* EKr = (float*)(ws + 196608);              //  65,536 B
    unsigned short* WT = (unsigned short*)(ws + 262144);   //  98,304 B (3x128x128 bf16)
    unsigned short* qb = (unsigned short*)(ws + 524288);   // 41,943,040 B
    unsigned short* kb = (unsigned short*)(ws + 42467328); // 41,943,040 B
    unsigned short* vb = (unsigned short*)(ws + 84410368); // 41,943,040 B (end 126,353,408)
    float* outp = (float*)d_out;

    enc_tables<<<dim3(128),      256, 0, stream>>>(Wq, bq, Wk, bk, EQc, EQr, EKc, EKr);
    prep_w    <<<dim3(3, 128),   128, 0, stream>>>(Wq, Wk, Wv, WT);
    qkv_mfma  <<<dim3(1280, 3),  256, 0, stream>>>(x, WT, EQc, EQr, EKc, EKr, bv, qb, kb, vb);
    attn_o    <<<dim3(256, 10),  256, 0, stream>>>((const bf16*)qb, (const bf16*)kb, (const bf16*)vb, Wo, bo, outp);
}

// Round 7
// 201.672 us; speedup vs baseline: 2.4519x; 1.7906x over previous
//
#include <hip/hip_runtime.h>
#include <hip/hip_bf16.h>

typedef __hip_bfloat16 bf16;
typedef short bf16x8 __attribute__((ext_vector_type(8)));
typedef float f32x4 __attribute__((ext_vector_type(4)));

static __device__ __forceinline__ unsigned short f2bf(float f) {
    unsigned u = __float_as_uint(f);
    return (unsigned short)((u + 0x7fffu + ((u >> 16) & 1u)) >> 16);
}
static __device__ __forceinline__ unsigned pack2(float lo, float hi) {
    return (((unsigned)f2bf(hi)) << 16) | (unsigned)f2bf(lo);
}
static __device__ __forceinline__ float bflo(unsigned u) { return __uint_as_float(u << 16); }
static __device__ __forceinline__ float bfhi(unsigned u) { return __uint_as_float(u & 0xffff0000u); }

// ---------------------------------------------------------------------------
// Kernel 1: separable positional-encoding tables (all f32).
// ---------------------------------------------------------------------------
__global__ __launch_bounds__(256) void enc_tables(
    const float* __restrict__ Wq, const float* __restrict__ bq,
    const float* __restrict__ Wk, const float* __restrict__ bk,
    float* __restrict__ EQc, float* __restrict__ EQr,
    float* __restrict__ EKc, float* __restrict__ EKr)
{
    const int c   = blockIdx.x;
    const int ch  = threadIdx.x & 127;
    const int isk = threadIdx.x >> 7;
    const float* W = isk ? Wk : Wq;
    const float* b = isk ? bk : bq;
    const float FSTEP = (float)(3.14 / 200.0);
    float accC = 0.f, accR = 0.f;
    for (int fi = 0; fi < 32; ++fi) {
        float f = (float)fi * FSTEP;
        float a = (float)c * f;
        float s = sinf(a), co = cosf(a);
        accC = fmaf(s,  W[fi * 128 + ch],        accC);
        accC = fmaf(co, W[(32 + fi) * 128 + ch], accC);
        accR = fmaf(s,  W[(64 + fi) * 128 + ch], accR);
        accR = fmaf(co, W[(96 + fi) * 128 + ch], accR);
    }
    accR += b[ch];
    (isk ? EKc : EQc)[c * 128 + ch] = accC;
    (isk ? EKr : EQr)[c * 128 + ch] = accR;
}

// ---------------------------------------------------------------------------
// Kernel 1b: transpose+convert weights: WT[j][n][k] = W_j[k][n] as bf16.
// j: 0=Wq 1=Wk 2=Wv 3=Wo
// ---------------------------------------------------------------------------
__global__ __launch_bounds__(128) void prep_w(
    const float* __restrict__ Wq, const float* __restrict__ Wk,
    const float* __restrict__ Wv, const float* __restrict__ Wo,
    unsigned short* __restrict__ WT)
{
    const int j = blockIdx.x;       // 0..3
    const int n = blockIdx.y;       // 0..127
    const int k = threadIdx.x;      // 0..127
    const float* W = (j == 0) ? Wq : ((j == 1) ? Wk : ((j == 2) ? Wv : Wo));
    WT[((size_t)j * 128 + n) * 128 + k] = f2bf(W[k * 128 + n]);
}

// ---------------------------------------------------------------------------
// Kernel 2: QKV GEMM via MFMA (unchanged from round 6).
// ---------------------------------------------------------------------------
__global__ __launch_bounds__(256) void qkv_mfma(
    const float* __restrict__ x,
    const unsigned short* __restrict__ WT,
    const float* __restrict__ EQc, const float* __restrict__ EQr,
    const float* __restrict__ EKc, const float* __restrict__ EKr,
    const float* __restrict__ bv,
    unsigned short* __restrict__ qb, unsigned short* __restrict__ kb,
    unsigned short* __restrict__ vb)
{
    __shared__ unsigned short xs[128 * 128];
    __shared__ unsigned short wt[128 * 128];
    const int tid = threadIdx.x;
    const int mb = blockIdx.x;    // 0..1279
    const int nb = blockIdx.y;    // 0: q, 1: k, 2: v

    const float* xbase = x + (size_t)mb * (128 * 128);
#pragma unroll
    for (int i = 0; i < 8; ++i) {
        int idx = tid + i * 256;
        int m = idx >> 4, c8 = (idx & 15) << 3;
        float4 f0 = *(const float4*)(xbase + m * 128 + c8);
        float4 f1 = *(const float4*)(xbase + m * 128 + c8 + 4);
        unsigned off = (unsigned)(m * 256 + ((c8 * 2) ^ ((m & 7) << 4)));
        unsigned* d = (unsigned*)((char*)xs + off);
        d[0] = pack2(f0.x, f0.y); d[1] = pack2(f0.z, f0.w);
        d[2] = pack2(f1.x, f1.y); d[3] = pack2(f1.z, f1.w);
    }
    const unsigned short* wsrc = WT + (size_t)nb * (128 * 128);
#pragma unroll
    for (int i = 0; i < 8; ++i) {
        int idx = tid + i * 256;
        int n = idx >> 4, cb = (idx & 15) << 4;
        uint4 r = *(const uint4*)(wsrc + n * 128 + (idx & 15) * 8);
        unsigned off = (unsigned)(n * 256 + (cb ^ ((n & 7) << 4)));
        *(uint4*)((char*)wt + off) = r;
    }
    __syncthreads();

    const int lane = tid & 63;
    const int wv4  = tid >> 6;
    const int wbase = wv4 << 5;
    const int lo16 = (lane >> 4) << 4;
    const int lx   = (lane & 7) << 4;

    f32x4 acc[2][8] = {};
#pragma unroll
    for (int ks = 0; ks < 4; ++ks) {
        bf16x8 af[2], bfr[8];
        const int kb0 = ks * 64 + lo16;
#pragma unroll
        for (int rt = 0; rt < 2; ++rt) {
            int row = wbase + rt * 16 + (lane & 15);
            af[rt] = *(const bf16x8*)((const char*)xs + row * 256 + (kb0 ^ lx));
        }
#pragma unroll
        for (int ct = 0; ct < 8; ++ct) {
            int n = ct * 16 + (lane & 15);
            bfr[ct] = *(const bf16x8*)((const char*)wt + n * 256 + (kb0 ^ lx));
        }
#pragma unroll
        for (int rt = 0; rt < 2; ++rt)
#pragma unroll
            for (int ct = 0; ct < 8; ++ct)
                acc[rt][ct] = __builtin_amdgcn_mfma_f32_16x16x32_bf16(
                    af[rt], bfr[ct], acc[rt][ct], 0, 0, 0);
    }

    const int rowimg = mb & 127;
    unsigned short* dstp = (nb == 0) ? qb : ((nb == 1) ? kb : vb);
#pragma unroll
    for (int rt = 0; rt < 2; ++rt) {
#pragma unroll
        for (int r = 0; r < 4; ++r) {
            int m = wbase + rt * 16 + ((lane >> 4) << 2) + r;
            size_t t = (size_t)mb * 128 + m;
#pragma unroll
            for (int ct = 0; ct < 8; ++ct) {
                int ch = ct * 16 + (lane & 15);
                float val = acc[rt][ct][r];
                if (nb == 0)      val += EQc[m * 128 + ch] + EQr[rowimg * 128 + ch];
                else if (nb == 1) val += EKc[m * 128 + ch] + EKr[rowimg * 128 + ch];
                else              val += bv[ch];
                dstp[t * 128 + ch] = f2bf(val);
            }
        }
    }
}

// ---------------------------------------------------------------------------
// Kernel 3: windowed attention + O-proj, full MFMA.
// 512 thr = 8 waves: wave w -> head h=w>>1, query-half=w&1.
// Phases: stage(q,k,vT) | S^T=mfma(k,q) + col-softmax | P->LDS (over q/k) |
//         aoT=mfma(vT,P^T) | ao->LDS (over vT) | outT=mfma(WoT,ao) |
//         ols (over q/k) | coalesced f32 store.
// LDS (bytes): q[64]x288 @0, k[64]x288 @18432, vT[128]x144 @36864 = 55296.
//   P_h = h*9216 (over q|k), ao @36864 (over vT), ols f32 [64]x544 @0.
// ---------------------------------------------------------------------------
__global__ __launch_bounds__(512) void attn_o_mfma(
    const unsigned short* __restrict__ qb, const unsigned short* __restrict__ kb,
    const unsigned short* __restrict__ vb,
    const unsigned short* __restrict__ WoT, const float* __restrict__ bo,
    float* __restrict__ out)
{
    __shared__ __align__(16) char smem[55296];
    const int QOFF = 0, KOFF = 18432, VOFF = 36864, AOOFF = 36864;

    const int w = blockIdx.x;       // 0..255
    const int b = blockIdx.y;       // 0..9
    const int wy = w >> 4, wx = w & 15;
    const int g4 = b >> 1;          // bn = 2
    int swy = wy, swx = wx;
    if (g4 == 0)      { if (wy < 15) swy = wy + 1; }   // up
    else if (g4 == 1) { if (wy > 0)  swy = wy - 1; }   // down
    else if (g4 == 2) { if (wx < 15) swx = wx + 1; }   // left
    else if (g4 == 3) { if (wx > 0)  swx = wx - 1; }   // right
    const int tid = threadIdx.x;
    const size_t bbase = (size_t)b * 16384;

    // ---- stage q, k (64 tok x 128 ch, row stride 288 B) ----
#pragma unroll
    for (int i = 0; i < 2; ++i) {
        int idx = tid + i * 512;                 // 0..1023
        int m = idx >> 4, c8 = (idx & 15) << 3;
        int qt = ((wy * 8 + (m >> 3)) << 7) + (wx << 3) + (m & 7);
        uint4 rq = *(const uint4*)(qb + (bbase + qt) * 128 + c8);
        *(uint4*)(smem + QOFF + m * 288 + c8 * 2) = rq;
        int kt = ((swy * 8 + (m >> 3)) << 7) + (swx << 3) + (m & 7);
        uint4 rk = *(const uint4*)(kb + (bbase + kt) * 128 + c8);
        *(uint4*)(smem + KOFF + m * 288 + c8 * 2) = rk;
    }
    // ---- stage vT (128 ch x 64 tok, row stride 144 B), transpose-on-write ----
#pragma unroll
    for (int i = 0; i < 2; ++i) {
        int tok = tid & 63, cs = (tid >> 6) + i * 8;   // ch-seg 0..15
        int c8 = cs << 3;
        int vt = ((swy * 8 + (tok >> 3)) << 7) + (swx << 3) + (tok & 7);
        uint4 rv = *(const uint4*)(vb + (bbase + vt) * 128 + c8);
        unsigned short e[8] = {
            (unsigned short)rv.x, (unsigned short)(rv.x >> 16),
            (unsigned short)rv.y, (unsigned short)(rv.y >> 16),
            (unsigned short)rv.z, (unsigned short)(rv.z >> 16),
            (unsigned short)rv.w, (unsigned short)(rv.w >> 16) };
#pragma unroll
        for (int t2 = 0; t2 < 8; ++t2)
            *(unsigned short*)(smem + VOFF + (c8 + t2) * 144 + tok * 2) = e[t2];
    }
    __syncthreads();   // (1)

    const int lane = tid & 63;
    const int w8 = tid >> 6;            // wave 0..7
    const int h = w8 >> 1, half = w8 & 1;
    const int il = lane & 15, g = lane >> 4;
    const int cbase = h * 64 + g * 16;  // byte offset of this lane's 8-ch K-seg

    // ---- S^T = mfma(k, q): D[j][i], per wave: 4 j-tiles x 2 i-tiles ----
    bf16x8 ak[4], bq2[2];
#pragma unroll
    for (int mj = 0; mj < 4; ++mj)
        ak[mj] = *(const bf16x8*)(smem + KOFF + (mj * 16 + il) * 288 + cbase);
#pragma unroll
    for (int nt = 0; nt < 2; ++nt)
        bq2[nt] = *(const bf16x8*)(smem + QOFF + ((2 * half + nt) * 16 + il) * 288 + cbase);
    f32x4 s[4][2] = {};
#pragma unroll
    for (int mj = 0; mj < 4; ++mj)
#pragma unroll
        for (int nt = 0; nt < 2; ++nt)
            s[mj][nt] = __builtin_amdgcn_mfma_f32_16x16x32_bf16(ak[mj], bq2[nt], s[mj][nt], 0, 0, 0);

    // ---- column softmax (col i = query), no max-subtract ----
    const float scale = 0.17677669529663689f;   // 32^-0.5
    float p[4][2][4];
    float csum[2] = {0.f, 0.f};
#pragma unroll
    for (int mj = 0; mj < 4; ++mj)
#pragma unroll
        for (int nt = 0; nt < 2; ++nt)
#pragma unroll
            for (int r = 0; r < 4; ++r) {
                float e = __expf(s[mj][nt][r] * scale);
                p[mj][nt][r] = e;
                csum[nt] += e;
            }
#pragma unroll
    for (int nt = 0; nt < 2; ++nt) {
        csum[nt] += __shfl_xor(csum[nt], 16);
        csum[nt] += __shfl_xor(csum[nt], 32);
    }
    float inv[2] = {1.f / csum[0], 1.f / csum[1]};

    __syncthreads();   // (2) q,k reads done everywhere; P may overwrite them

    // ---- write normalized P^T to LDS: P_h[i][j], row stride 144 B ----
    {
        char* pb = smem + h * 9216;
#pragma unroll
        for (int nt = 0; nt < 2; ++nt) {
            int i = (2 * half + nt) * 16 + il;
#pragma unroll
            for (int mj = 0; mj < 4; ++mj) {
                unsigned w0 = pack2(p[mj][nt][0] * inv[nt], p[mj][nt][1] * inv[nt]);
                unsigned w1 = pack2(p[mj][nt][2] * inv[nt], p[mj][nt][3] * inv[nt]);
                char* base = pb + i * 144 + mj * 32 + g * 8;
                *(unsigned*)base = w0;
                *(unsigned*)(base + 4) = w1;
            }
        }
    }
    // no barrier: PV reads only self-written P columns

    // ---- aoT = mfma(vT, P^T): per wave 2 ch-tiles x 2 tok-tiles, K=64 ----
    f32x4 apv[2][2] = {};
#pragma unroll
    for (int ks = 0; ks < 2; ++ks) {
        bf16x8 av[2], bp[2];
#pragma unroll
        for (int mc = 0; mc < 2; ++mc)
            av[mc] = *(const bf16x8*)(smem + VOFF + (h * 32 + mc * 16 + il) * 144 + ks * 64 + g * 16);
#pragma unroll
        for (int nt = 0; nt < 2; ++nt)
            bp[nt] = *(const bf16x8*)(smem + h * 9216 + ((2 * half + nt) * 16 + il) * 144 + ks * 64 + g * 16);
#pragma unroll
        for (int mc = 0; mc < 2; ++mc)
#pragma unroll
            for (int nt = 0; nt < 2; ++nt)
                apv[mc][nt] = __builtin_amdgcn_mfma_f32_16x16x32_bf16(av[mc], bp[nt], apv[mc][nt], 0, 0, 0);
    }
    __syncthreads();   // (3) vT reads done; ao may overwrite

    // ---- ao -> LDS: ao[tok][c] bf16, row stride 272 B ----
#pragma unroll
    for (int nt = 0; nt < 2; ++nt) {
        int i = (2 * half + nt) * 16 + il;
#pragma unroll
        for (int mc = 0; mc < 2; ++mc) {
            int c0 = h * 32 + mc * 16 + g * 4;
            unsigned w0 = pack2(apv[mc][nt][0], apv[mc][nt][1]);
            unsigned w1 = pack2(apv[mc][nt][2], apv[mc][nt][3]);
            char* base = smem + AOOFF + i * 272 + c0 * 2;
            *(unsigned*)base = w0;
            *(unsigned*)(base + 4) = w1;
        }
    }
    __syncthreads();   // (4) ao complete (cross-wave channels)

    // ---- outT = mfma(WoT, ao): wave w8 -> out-ch tile n=16*w8.., 4 tok-tiles ----
    bf16x8 awo[4];
#pragma unroll
    for (int ks = 0; ks < 4; ++ks)
        awo[ks] = *(const bf16x8*)(WoT + (16 * w8 + il) * 128 + ks * 32 + g * 8);
    f32x4 aco[4] = {};
#pragma unroll
    for (int ks = 0; ks < 4; ++ks) {
#pragma unroll
        for (int nt = 0; nt < 4; ++nt) {
            bf16x8 bao = *(const bf16x8*)(smem + AOOFF + (nt * 16 + il) * 272 + ks * 64 + g * 16);
            aco[nt] = __builtin_amdgcn_mfma_f32_16x16x32_bf16(awo[ks], bao, aco[nt], 0, 0, 0);
        }
    }

    // ---- ols[tok][n] f32 (row stride 544 B, over q/k region) ----
    float bov[4];
#pragma unroll
    for (int r = 0; r < 4; ++r) bov[r] = bo[16 * w8 + g * 4 + r];
    float* ols = (float*)smem;
#pragma unroll
    for (int nt = 0; nt < 4; ++nt)
#pragma unroll
        for (int r = 0; r < 4; ++r)
            ols[(nt * 16 + il) * 136 + 16 * w8 + g * 4 + r] = aco[nt][r] + bov[r];
    __syncthreads();   // (5)

    // ---- coalesced f32 store ----
#pragma unroll
    for (int i = 0; i < 4; ++i) {
        int idx = tid + i * 512;                 // 2048 float4 chunks
        int m = idx >> 5, c4 = (idx & 31) << 2;
        float4 o4 = *(const float4*)&ols[m * 136 + c4];
        int tok = ((wy * 8 + (m >> 3)) << 7) + (wx << 3) + (m & 7);
        *(float4*)(out + (bbase + tok) * 128 + c4) = o4;
    }
}

// ---------------------------------------------------------------------------
extern "C" void kernel_launch(void* const* d_in, const int* in_sizes, int n_in,
                              void* d_out, int out_size, void* d_ws, size_t ws_size,
                              hipStream_t stream)
{
    const float* x  = (const float*)d_in[0];
    const float* Wq = (const float*)d_in[1];
    const float* bq = (const float*)d_in[2];
    const float* Wk = (const float*)d_in[3];
    const float* bk = (const float*)d_in[4];
    const float* Wv = (const float*)d_in[5];
    const float* bv = (const float*)d_in[6];
    const float* Wo = (const float*)d_in[7];
    const float* bo = (const float*)d_in[8];

    char* ws = (char*)d_ws;
    float* EQc = (float*)(ws);                       //  65,536 B
    float* EQr = (float*)(ws + 65536);               //  65,536 B
    float* EKc = (float*)(ws + 131072);              //  65,536 B
    float* EKr = (float*)(ws + 196608);              //  65,536 B
    unsigned short* WT = (unsigned short*)(ws + 262144);   // 131,072 B (4x128x128 bf16)
    unsigned short* qb = (unsigned short*)(ws + 393216);   // 41,943,040 B
    unsigned short* kb = (unsigned short*)(ws + 42336256); // 41,943,040 B
    unsigned short* vb = (unsigned short*)(ws + 84279296); // 41,943,040 B (end 126,222,336)
    float* outp = (float*)d_out;

    enc_tables <<<dim3(128),      256, 0, stream>>>(Wq, bq, Wk, bk, EQc, EQr, EKc, EKr);
    prep_w     <<<dim3(4, 128),   128, 0, stream>>>(Wq, Wk, Wv, Wo, WT);
    qkv_mfma   <<<dim3(1280, 3),  256, 0, stream>>>(x, WT, EQc, EQr, EKc, EKr, bv, qb, kb, vb);
    attn_o_mfma<<<dim3(256, 10),  512, 0, stream>>>(qb, kb, vb, WT + 3 * 16384, bo, outp);
}

// Round 8
// 148.165 us; speedup vs baseline: 3.3374x; 1.3611x over previous
//
#include <hip/hip_runtime.h>
#include <hip/hip_bf16.h>

typedef __hip_bfloat16 bf16;
typedef short bf16x8 __attribute__((ext_vector_type(8)));
typedef float f32x4 __attribute__((ext_vector_type(4)));

static __device__ __forceinline__ unsigned short f2bf(float f) {
    unsigned u = __float_as_uint(f);
    return (unsigned short)((u + 0x7fffu + ((u >> 16) & 1u)) >> 16);
}
static __device__ __forceinline__ unsigned pack2(float lo, float hi) {
    return (((unsigned)f2bf(hi)) << 16) | (unsigned)f2bf(lo);
}
static __device__ __forceinline__ float bflo(unsigned u) { return __uint_as_float(u << 16); }
static __device__ __forceinline__ float bfhi(unsigned u) { return __uint_as_float(u & 0xffff0000u); }

// ---------------------------------------------------------------------------
// Kernel 1: separable positional-encoding tables (all f32).
// ---------------------------------------------------------------------------
__global__ __launch_bounds__(256) void enc_tables(
    const float* __restrict__ Wq, const float* __restrict__ bq,
    const float* __restrict__ Wk, const float* __restrict__ bk,
    float* __restrict__ EQc, float* __restrict__ EQr,
    float* __restrict__ EKc, float* __restrict__ EKr)
{
    const int c   = blockIdx.x;
    const int ch  = threadIdx.x & 127;
    const int isk = threadIdx.x >> 7;
    const float* W = isk ? Wk : Wq;
    const float* b = isk ? bk : bq;
    const float FSTEP = (float)(3.14 / 200.0);
    float accC = 0.f, accR = 0.f;
    for (int fi = 0; fi < 32; ++fi) {
        float f = (float)fi * FSTEP;
        float a = (float)c * f;
        float s = sinf(a), co = cosf(a);
        accC = fmaf(s,  W[fi * 128 + ch],        accC);
        accC = fmaf(co, W[(32 + fi) * 128 + ch], accC);
        accR = fmaf(s,  W[(64 + fi) * 128 + ch], accR);
        accR = fmaf(co, W[(96 + fi) * 128 + ch], accR);
    }
    accR += b[ch];
    (isk ? EKc : EQc)[c * 128 + ch] = accC;
    (isk ? EKr : EQr)[c * 128 + ch] = accR;
}

// ---------------------------------------------------------------------------
// Kernel 1b: transpose+convert weights: WT[j][n][k] = W_j[k][n] as bf16.
// j: 0=Wq 1=Wk 2=Wv 3=Wo
// ---------------------------------------------------------------------------
__global__ __launch_bounds__(128) void prep_w(
    const float* __restrict__ Wq, const float* __restrict__ Wk,
    const float* __restrict__ Wv, const float* __restrict__ Wo,
    unsigned short* __restrict__ WT)
{
    const int j = blockIdx.x;       // 0..3
    const int n = blockIdx.y;       // 0..127
    const int k = threadIdx.x;      // 0..127
    const float* W = (j == 0) ? Wq : ((j == 1) ? Wk : ((j == 2) ? Wv : Wo));
    WT[((size_t)j * 128 + n) * 128 + k] = f2bf(W[k * 128 + n]);
}

// ---------------------------------------------------------------------------
// Kernel 2: QKV GEMM via MFMA, swapped operands: D[ch][token] = mfma(W, x).
// x (shared across waves) staged in 32 KB LDS; W A-fragments read directly
// from global WT (L2-resident). Wave w owns ch rows 32w..32w+31 and loops
// all 8 token-tiles. Epilogue: float4 enc loads + packed 8B stores.
// ---------------------------------------------------------------------------
__global__ __launch_bounds__(256, 4) void qkv_mfma(
    const float* __restrict__ x,
    const unsigned short* __restrict__ WT,
    const float* __restrict__ EQc, const float* __restrict__ EQr,
    const float* __restrict__ EKc, const float* __restrict__ EKr,
    const float* __restrict__ bv,
    unsigned short* __restrict__ qb, unsigned short* __restrict__ kb,
    unsigned short* __restrict__ vb)
{
    __shared__ unsigned short xs[128 * 128];   // 32 KB, swizzled [tok][k]
    const int tid = threadIdx.x;
    const int mb = blockIdx.x;    // 0..1279
    const int nb = blockIdx.y;    // 0: q, 1: k, 2: v

    // stage x tile (f32 -> bf16, swizzled): 2048 chunks of 8 elems
    const float* xbase = x + (size_t)mb * (128 * 128);
#pragma unroll
    for (int i = 0; i < 8; ++i) {
        int idx = tid + i * 256;
        int m = idx >> 4, c8 = (idx & 15) << 3;
        float4 f0 = *(const float4*)(xbase + m * 128 + c8);
        float4 f1 = *(const float4*)(xbase + m * 128 + c8 + 4);
        unsigned off = (unsigned)(m * 256 + ((c8 * 2) ^ ((m & 7) << 4)));
        unsigned* d = (unsigned*)((char*)xs + off);
        d[0] = pack2(f0.x, f0.y); d[1] = pack2(f0.z, f0.w);
        d[2] = pack2(f1.x, f1.y); d[3] = pack2(f1.z, f1.w);
    }

    const int lane = tid & 63;
    const int wv4  = tid >> 6;          // wave id 0..3
    const int il = lane & 15, g = lane >> 4;
    const int chb = wv4 << 5;           // wave's 32-channel base

    // prefetch A-fragments (W rows = output channels) from global WT
    const unsigned short* wsrc = WT + (size_t)nb * (128 * 128);
    bf16x8 aw[2][4];
#pragma unroll
    for (int ct = 0; ct < 2; ++ct)
#pragma unroll
        for (int ks = 0; ks < 4; ++ks)
            aw[ct][ks] = *(const bf16x8*)(wsrc + (chb + ct * 16 + il) * 128 + ks * 32 + g * 8);

    __syncthreads();

    // MFMA main: acc[mt][ct] = D[ch-tile ct][token-tile mt]
    const int lx = (il & 7) << 4;
    f32x4 acc[8][2] = {};
#pragma unroll
    for (int ks = 0; ks < 4; ++ks) {
        const int kb0 = ks * 64 + g * 16;
#pragma unroll
        for (int mt = 0; mt < 8; ++mt) {
            bf16x8 bx = *(const bf16x8*)((const char*)xs + (mt * 16 + il) * 256 + (kb0 ^ lx));
            acc[mt][0] = __builtin_amdgcn_mfma_f32_16x16x32_bf16(aw[0][ks], bx, acc[mt][0], 0, 0, 0);
            acc[mt][1] = __builtin_amdgcn_mfma_f32_16x16x32_bf16(aw[1][ks], bx, acc[mt][1], 0, 0, 0);
        }
    }

    // epilogue: lane holds token = mt*16+il, channels ch0..ch0+3 (ch0 = chb+ct*16+g*4)
    const int rowimg = mb & 127;
    const float* Ec = (nb == 0) ? EQc : EKc;
    const float* Er = (nb == 0) ? EQr : EKr;
    unsigned short* dstp = (nb == 0) ? qb : ((nb == 1) ? kb : vb);
#pragma unroll
    for (int ct = 0; ct < 2; ++ct) {
        const int ch0 = chb + ct * 16 + (g << 2);
        float4 er;
        if (nb < 2) er = *(const float4*)(Er + rowimg * 128 + ch0);
        else        er = *(const float4*)(bv + ch0);
#pragma unroll
        for (int mt = 0; mt < 8; ++mt) {
            const int m = mt * 16 + il;
            float v0 = acc[mt][ct][0], v1 = acc[mt][ct][1];
            float v2 = acc[mt][ct][2], v3 = acc[mt][ct][3];
            if (nb < 2) {
                float4 ec = *(const float4*)(Ec + m * 128 + ch0);
                v0 += ec.x + er.x; v1 += ec.y + er.y;
                v2 += ec.z + er.z; v3 += ec.w + er.w;
            } else {
                v0 += er.x; v1 += er.y; v2 += er.z; v3 += er.w;
            }
            uint2 o;
            o.x = pack2(v0, v1);
            o.y = pack2(v2, v3);
            *(uint2*)(dstp + ((size_t)mb * 128 + m) * 128 + ch0) = o;
        }
    }
}

// ---------------------------------------------------------------------------
// Kernel 3: windowed attention + O-proj, full MFMA (unchanged from round 7).
// ---------------------------------------------------------------------------
__global__ __launch_bounds__(512) void attn_o_mfma(
    const unsigned short* __restrict__ qb, const unsigned short* __restrict__ kb,
    const unsigned short* __restrict__ vb,
    const unsigned short* __restrict__ WoT, const float* __restrict__ bo,
    float* __restrict__ out)
{
    __shared__ __align__(16) char smem[55296];
    const int QOFF = 0, KOFF = 18432, VOFF = 36864, AOOFF = 36864;

    const int w = blockIdx.x;       // 0..255
    const int b = blockIdx.y;       // 0..9
    const int wy = w >> 4, wx = w & 15;
    const int g4 = b >> 1;          // bn = 2
    int swy = wy, swx = wx;
    if (g4 == 0)      { if (wy < 15) swy = wy + 1; }   // up
    else if (g4 == 1) { if (wy > 0)  swy = wy - 1; }   // down
    else if (g4 == 2) { if (wx < 15) swx = wx + 1; }   // left
    else if (g4 == 3) { if (wx > 0)  swx = wx - 1; }   // right
    const int tid = threadIdx.x;
    const size_t bbase = (size_t)b * 16384;

#pragma unroll
    for (int i = 0; i < 2; ++i) {
        int idx = tid + i * 512;
        int m = idx >> 4, c8 = (idx & 15) << 3;
        int qt = ((wy * 8 + (m >> 3)) << 7) + (wx << 3) + (m & 7);
        uint4 rq = *(const uint4*)(qb + (bbase + qt) * 128 + c8);
        *(uint4*)(smem + QOFF + m * 288 + c8 * 2) = rq;
        int kt = ((swy * 8 + (m >> 3)) << 7) + (swx << 3) + (m & 7);
        uint4 rk = *(const uint4*)(kb + (bbase + kt) * 128 + c8);
        *(uint4*)(smem + KOFF + m * 288 + c8 * 2) = rk;
    }
#pragma unroll
    for (int i = 0; i < 2; ++i) {
        int tok = tid & 63, cs = (tid >> 6) + i * 8;
        int c8 = cs << 3;
        int vt = ((swy * 8 + (tok >> 3)) << 7) + (swx << 3) + (tok & 7);
        uint4 rv = *(const uint4*)(vb + (bbase + vt) * 128 + c8);
        unsigned short e[8] = {
            (unsigned short)rv.x, (unsigned short)(rv.x >> 16),
            (unsigned short)rv.y, (unsigned short)(rv.y >> 16),
            (unsigned short)rv.z, (unsigned short)(rv.z >> 16),
            (unsigned short)rv.w, (unsigned short)(rv.w >> 16) };
#pragma unroll
        for (int t2 = 0; t2 < 8; ++t2)
            *(unsigned short*)(smem + VOFF + (c8 + t2) * 144 + tok * 2) = e[t2];
    }
    __syncthreads();   // (1)

    const int lane = tid & 63;
    const int w8 = tid >> 6;
    const int h = w8 >> 1, half = w8 & 1;
    const int il = lane & 15, g = lane >> 4;
    const int cbase = h * 64 + g * 16;

    bf16x8 ak[4], bq2[2];
#pragma unroll
    for (int mj = 0; mj < 4; ++mj)
        ak[mj] = *(const bf16x8*)(smem + KOFF + (mj * 16 + il) * 288 + cbase);
#pragma unroll
    for (int nt = 0; nt < 2; ++nt)
        bq2[nt] = *(const bf16x8*)(smem + QOFF + ((2 * half + nt) * 16 + il) * 288 + cbase);
    f32x4 s[4][2] = {};
#pragma unroll
    for (int mj = 0; mj < 4; ++mj)
#pragma unroll
        for (int nt = 0; nt < 2; ++nt)
            s[mj][nt] = __builtin_amdgcn_mfma_f32_16x16x32_bf16(ak[mj], bq2[nt], s[mj][nt], 0, 0, 0);

    const float scale = 0.17677669529663689f;
    float p[4][2][4];
    float csum[2] = {0.f, 0.f};
#pragma unroll
    for (int mj = 0; mj < 4; ++mj)
#pragma unroll
        for (int nt = 0; nt < 2; ++nt)
#pragma unroll
            for (int r = 0; r < 4; ++r) {
                float e = __expf(s[mj][nt][r] * scale);
                p[mj][nt][r] = e;
                csum[nt] += e;
            }
#pragma unroll
    for (int nt = 0; nt < 2; ++nt) {
        csum[nt] += __shfl_xor(csum[nt], 16);
        csum[nt] += __shfl_xor(csum[nt], 32);
    }
    float inv[2] = {1.f / csum[0], 1.f / csum[1]};

    __syncthreads();   // (2)

    {
        char* pb = smem + h * 9216;
#pragma unroll
        for (int nt = 0; nt < 2; ++nt) {
            int i = (2 * half + nt) * 16 + il;
#pragma unroll
            for (int mj = 0; mj < 4; ++mj) {
                unsigned w0 = pack2(p[mj][nt][0] * inv[nt], p[mj][nt][1] * inv[nt]);
                unsigned w1 = pack2(p[mj][nt][2] * inv[nt], p[mj][nt][3] * inv[nt]);
                char* base = pb + i * 144 + mj * 32 + g * 8;
                *(unsigned*)base = w0;
                *(unsigned*)(base + 4) = w1;
            }
        }
    }

    f32x4 apv[2][2] = {};
#pragma unroll
    for (int ks = 0; ks < 2; ++ks) {
        bf16x8 av[2], bp[2];
#pragma unroll
        for (int mc = 0; mc < 2; ++mc)
            av[mc] = *(const bf16x8*)(smem + VOFF + (h * 32 + mc * 16 + il) * 144 + ks * 64 + g * 16);
#pragma unroll
        for (int nt = 0; nt < 2; ++nt)
            bp[nt] = *(const bf16x8*)(smem + h * 9216 + ((2 * half + nt) * 16 + il) * 144 + ks * 64 + g * 16);
#pragma unroll
        for (int mc = 0; mc < 2; ++mc)
#pragma unroll
            for (int nt = 0; nt < 2; ++nt)
                apv[mc][nt] = __builtin_amdgcn_mfma_f32_16x16x32_bf16(av[mc], bp[nt], apv[mc][nt], 0, 0, 0);
    }
    __syncthreads();   // (3)

#pragma unroll
    for (int nt = 0; nt < 2; ++nt) {
        int i = (2 * half + nt) * 16 + il;
#pragma unroll
        for (int mc = 0; mc < 2; ++mc) {
            int c0 = h * 32 + mc * 16 + g * 4;
            unsigned w0 = pack2(apv[mc][nt][0], apv[mc][nt][1]);
            unsigned w1 = pack2(apv[mc][nt][2], apv[mc][nt][3]);
            char* base = smem + AOOFF + i * 272 + c0 * 2;
            *(unsigned*)base = w0;
            *(unsigned*)(base + 4) = w1;
        }
    }
    __syncthreads();   // (4)

    bf16x8 awo[4];
#pragma unroll
    for (int ks = 0; ks < 4; ++ks)
        awo[ks] = *(const bf16x8*)(WoT + (16 * w8 + il) * 128 + ks * 32 + g * 8);
    f32x4 aco[4] = {};
#pragma unroll
    for (int ks = 0; ks < 4; ++ks) {
#pragma unroll
        for (int nt = 0; nt < 4; ++nt) {
            bf16x8 bao = *(const bf16x8*)(smem + AOOFF + (nt * 16 + il) * 272 + ks * 64 + g * 16);
            aco[nt] = __builtin_amdgcn_mfma_f32_16x16x32_bf16(awo[ks], bao, aco[nt], 0, 0, 0);
        }
    }

    float bov[4];
#pragma unroll
    for (int r = 0; r < 4; ++r) bov[r] = bo[16 * w8 + g * 4 + r];
    float* ols = (float*)smem;
#pragma unroll
    for (int nt = 0; nt < 4; ++nt)
#pragma unroll
        for (int r = 0; r < 4; ++r)
            ols[(nt * 16 + il) * 136 + 16 * w8 + g * 4 + r] = aco[nt][r] + bov[r];
    __syncthreads();   // (5)

#pragma unroll
    for (int i = 0; i < 4; ++i) {
        int idx = tid + i * 512;
        int m = idx >> 5, c4 = (idx & 31) << 2;
        float4 o4 = *(const float4*)&ols[m * 136 + c4];
        int tok = ((wy * 8 + (m >> 3)) << 7) + (wx << 3) + (m & 7);
        *(float4*)(out + (bbase + tok) * 128 + c4) = o4;
    }
}

// ---------------------------------------------------------------------------
extern "C" void kernel_launch(void* const* d_in, const int* in_sizes, int n_in,
                              void* d_out, int out_size, void* d_ws, size_t ws_size,
                              hipStream_t stream)
{
    const float* x  = (const float*)d_in[0];
    const float* Wq = (const float*)d_in[1];
    const float* bq = (const float*)d_in[2];
    const float* Wk = (const float*)d_in[3];
    const float* bk = (const float*)d_in[4];
    const float* Wv = (const float*)d_in[5];
    const float* bv = (const float*)d_in[6];
    const float* Wo = (const float*)d_in[7];
    const float* bo = (const float*)d_in[8];

    char* ws = (char*)d_ws;
    float* EQc = (float*)(ws);                       //  65,536 B
    float* EQr = (float*)(ws + 65536);               //  65,536 B
    float* EKc = (float*)(ws + 131072);              //  65,536 B
    float* EKr = (float*)(ws + 196608);              //  65,536 B
    unsigned short* WT = (unsigned short*)(ws + 262144);   // 131,072 B (4x128x128 bf16)
    unsigned short* qb = (unsigned short*)(ws + 393216);   // 41,943,040 B
    unsigned short* kb = (unsigned short*)(ws + 42336256); // 41,943,040 B
    unsigned short* vb = (unsigned short*)(ws + 84279296); // 41,943,040 B (end 126,222,336)
    float* outp = (float*)d_out;

    enc_tables <<<dim3(128),      256, 0, stream>>>(Wq, bq, Wk, bk, EQc, EQr, EKc, EKr);
    prep_w     <<<dim3(4, 128),   128, 0, stream>>>(Wq, Wk, Wv, Wo, WT);
    qkv_mfma   <<<dim3(1280, 3),  256, 0, stream>>>(x, WT, EQc, EQr, EKc, EKr, bv, qb, kb, vb);
    attn_o_mfma<<<dim3(256, 10),  512, 0, stream>>>(qb, kb, vb, WT + 3 * 16384, bo, outp);
}